// Round 10
// baseline (246.467 us; speedup 1.0000x reference)
//
#include <hip/hip_runtime.h>
#include <cstdint>
#include <cstddef>

// Asymm_3d_spconv: ResContextBlock + ReconBlock over submanifold sparse convs.
// Round 10: gathers parked in LDS via __builtin_amdgcn_global_load_lds so all
// of a wave's taps are in flight simultaneously regardless of the register
// allocator (rounds 8/9 showed VGPR-resident batches get sunk). Per wave:
// 16 voxels x 32 co; 9 (conv) / 7 (recon) async 16B/lane stages into private
// 1KB LDS slots -> single s_waitcnt vmcnt(0) -> ds_read_b128 + MFMA per tap.
// Missing neighbors redirect to a zeroed dummy row in ws (all lanes issue the
// DMA -> no exec-mask holes). Numerics identical to round 9 (absmax 0.0156):
// bf16-hi intermediates, hi/lo-split weights, interleaved-K x.

#define SLOPE 0.01f
#define BN_EPS 1e-5f

typedef __attribute__((ext_vector_type(8))) short bf16x8;
typedef __attribute__((ext_vector_type(4))) float f32x4;

__device__ __forceinline__ float bflo(uint32_t w) {
    union { uint32_t i; float f; } v; v.i = w << 16; return v.f;
}
__device__ __forceinline__ float bfhi(uint32_t w) {
    union { uint32_t i; float f; } v; v.i = w & 0xffff0000u; return v.f;
}
__device__ __forceinline__ float bf2f(uint16_t u) {
    union { uint32_t i; float f; } v; v.i = ((uint32_t)u) << 16; return v.f;
}
__device__ __forceinline__ uint16_t f2bf(float f) {  // RNE
    union { float f; uint32_t i; } v; v.f = f;
    uint32_t x = v.i;
    return (uint16_t)((x + 0x7fffu + ((x >> 16) & 1u)) >> 16);
}

struct Taps9 { int t[9]; };
struct WSrcs { const void* p[8]; };  // W1,W12,W2,W3,Wr1,Wr2,Wr3,bnp

// Wf: 5 stages x [t9][T2][co32][k32] shorts, 18432 each.
// CIN16 stages (0,2): interleaved k (c=k>>1): T0=[wh,wh] dup, T1=[wl,0].
// CIN32 stages (1,3,4): k=channel: T0=wh, T1=wl. Stage 4 folds BN scale.
#define WFS     18432
#define WF_END  (5 * WFS)
#define BN_CNT  896
#define ZROW_OFF 3584   // byte offset of 128B zero row inside the bnf page

__device__ __forceinline__ int detect_f32_inline(const uint16_t* x16)
{
    int lane = threadIdx.x & 63;
    float a = bf2f(x16[4 * lane]);
    float b = bf2f(x16[4 * lane + 2]);
    int bad = (!(a > -16.f && a < 16.f)) || (!(b > -16.f && b < 16.f));
    return __ballot(bad) != 0ull;
}

__device__ __forceinline__ float readw(const void* p, int j, int f32)
{
    return f32 ? ((const float*)p)[j] : bf2f(((const uint16_t*)p)[j]);
}

// async global->LDS: 16B per lane, LDS dest = base + lane*16
__device__ __forceinline__ void gl_lds16(const uint16_t* g, uint16_t* l)
{
    __builtin_amdgcn_global_load_lds(
        (const __attribute__((address_space(1))) uint32_t*)g,
        (__attribute__((address_space(3))) uint32_t*)l, 16, 0, 0);
}

// ---------------------------------------------------------------------------
__global__ void prep_all(const uint16_t* __restrict__ xprobe, WSrcs srcs,
                         uint16_t* __restrict__ Wf, float* __restrict__ bnf)
{
    int f32 = detect_f32_inline(xprobe);
    int i = blockIdx.x * 256 + threadIdx.x;
    if (i < WF_END) {
        int s = i / WFS, r = i - s * WFS;
        int t = r >> 11, T = (r >> 10) & 1;
        int co = (r >> 5) & 31, k = r & 31;
        uint16_t outv;
        if (s == 0 || s == 2) {
            int c = k >> 1, p = k & 1;
            float w = readw(srcs.p[s == 0 ? 0 : 2], (t * 16 + c) * 32 + co, f32);
            uint16_t h = f2bf(w);
            outv = (T == 0) ? h : (p == 0 ? f2bf(w - bf2f(h)) : (uint16_t)0);
        } else {
            float w;
            if (s == 4) {
                int g = t / 3, kk = t - g * 3;
                const void* bnp = srcs.p[7];
                float ga = readw(bnp, (4 + g) * 128 + co, f32);
                float va = readw(bnp, (4 + g) * 128 + 96 + co, f32);
                float scl = ga * rsqrtf(va + BN_EPS);
                w = readw(srcs.p[4 + g], (kk * 32 + k) * 32 + co, f32) * scl;
            } else {
                w = readw(srcs.p[s == 1 ? 1 : 3], (t * 32 + k) * 32 + co, f32);
            }
            uint16_t h = f2bf(w);
            outv = (T == 0) ? h : f2bf(w - bf2f(h));
        }
        Wf[i] = outv;
    } else if (i < WF_END + BN_CNT) {
        bnf[i - WF_END] = readw(srcs.p[7], i - WF_END, f32);
    } else if (i < WF_END + BN_CNT + 64) {
        // zero dummy row (128B) for masked-neighbor DMA redirect
        ((uint16_t*)((char*)bnf + ZROW_OFF))[i - WF_END - BN_CNT] = 0;
    }
}

// x [N,16] -> interleaved hi/lo rows (exact): short[row*32 + 2c]=h, [+1]=l
__global__ void canon_x3(const void* __restrict__ xsrc,
                         uint32_t* __restrict__ xi, int total)
{
    int f32 = detect_f32_inline((const uint16_t*)xsrc);
    for (int i = blockIdx.x * blockDim.x + threadIdx.x; i < total;
         i += gridDim.x * blockDim.x) {
        float v = f32 ? ((const float*)xsrc)[i]
                      : bf2f(((const uint16_t*)xsrc)[i]);
        int row = i >> 4, c = i & 15;
        uint16_t h = f2bf(v);
        uint16_t l = f2bf(v - bf2f(h));
        xi[(size_t)row * 16 + c] = (uint32_t)h | ((uint32_t)l << 16);
    }
}

// ---------------------------------------------------------------------------
// conv v6: 64B feat rows; 256 thr = 4 waves; wave = 16 vox x 32 co. Async
// LDS-parked gathers (9 x 1KB/wave), single vmcnt drain, then MFMA.
// ---------------------------------------------------------------------------
struct ConvJob {
    const uint16_t* feat;    // [N][32] shorts (64B rows)
    const uint16_t* Wf;      // stage base [9][2][32][32]
    const float*    bn;      // 128 floats gamma/beta/mean/var
    const uint16_t* addsrc;  // nullable [N][32] bf16-hi
    uint16_t*       out;     // [N][32] bf16-hi
    Taps9 taps;
};

#define MFMA_BF16(A, B, C) __builtin_amdgcn_mfma_f32_16x16x32_bf16(A, B, C, 0, 0, 0)

__launch_bounds__(256)
__global__ void conv_mfma6(ConvJob j0, ConvJob j1,
                           const int* __restrict__ nbr,
                           const uint16_t* __restrict__ zrow, int N)
{
    __shared__ uint16_t stage[4][9][512];   // 36864 B
    const ConvJob J = (blockIdx.y == 1) ? j1 : j0;
    const int tid = threadIdx.x;
    const int w = tid >> 6, lane = tid & 63;
    const int m = lane & 15, q = lane >> 4;
    const int n0 = blockIdx.x * 64 + w * 16;

    int rows[9];
#pragma unroll
    for (int t = 0; t < 9; ++t) {
        int n = n0 + m;
        rows[t] = (n < N) ? nbr[(size_t)J.taps.t[t] * N + n] : -1;
    }
#pragma unroll
    for (int t = 0; t < 9; ++t) {
        const uint16_t* g = (rows[t] >= 0)
            ? J.feat + (size_t)rows[t] * 32 + q * 8
            : zrow + q * 8;
        gl_lds16(g, &stage[w][t][0]);
    }
    asm volatile("s_waitcnt vmcnt(0)" ::: "memory");

    f32x4 acc0 = {0.f, 0.f, 0.f, 0.f}, acc1 = {0.f, 0.f, 0.f, 0.f};
#pragma unroll
    for (int t = 0; t < 9; ++t) {
        bf16x8 A = *(const bf16x8*)&stage[w][t][lane * 8];
        const uint16_t* wb = J.Wf + t * 2048 + m * 32 + q * 8;
        bf16x8 B00 = *(const bf16x8*)(wb);            // T0 ot0
        bf16x8 B10 = *(const bf16x8*)(wb + 1024);     // T1 ot0
        bf16x8 B01 = *(const bf16x8*)(wb + 512);      // T0 ot1
        bf16x8 B11 = *(const bf16x8*)(wb + 1536);     // T1 ot1
        acc0 = MFMA_BF16(A, B00, acc0);
        acc0 = MFMA_BF16(A, B10, acc0);
        acc1 = MFMA_BF16(A, B01, acc1);
        acc1 = MFMA_BF16(A, B11, acc1);
    }

    // epilogue: C layout col=lane&15 (out-ch), row=quad*4+reg (voxel)
#pragma unroll
    for (int ot = 0; ot < 2; ++ot) {
        int ch = ot * 16 + m;
        float ga = J.bn[ch], be = J.bn[32 + ch];
        float mu = J.bn[64 + ch], va = J.bn[96 + ch];
        float s = ga * rsqrtf(va + BN_EPS);
        float b = be - mu * s;
        f32x4 a = ot ? acc1 : acc0;
#pragma unroll
        for (int r = 0; r < 4; ++r) {
            int vox = n0 + q * 4 + r;
            if (vox >= N) continue;
            float xv = a[r];
            xv = (xv >= 0.f) ? xv : SLOPE * xv;
            float o = xv * s + b;
            if (J.addsrc) o += bf2f(J.addsrc[(size_t)vox * 32 + ch]);
            J.out[(size_t)vox * 32 + ch] = f2bf(o);
        }
    }
}

// ---------------------------------------------------------------------------
// recon v6: 7 unique taps (center shared across the 3 groups), LDS-parked
// gathers, sigmoid per group, gate-multiply by y.
// ---------------------------------------------------------------------------
__launch_bounds__(256)
__global__ void recon_mfma6(const uint16_t* __restrict__ y16,
                            const uint16_t* __restrict__ xprobe,
                            const int* __restrict__ nbr,
                            const uint16_t* __restrict__ Wf4,
                            const float* __restrict__ bnf,
                            const uint16_t* __restrict__ zrow,
                            void* __restrict__ out_, int N)
{
    __shared__ uint16_t stage[4][7][512];   // 28672 B
    const int out_f32 = detect_f32_inline(xprobe);
    const int tid = threadIdx.x;
    const int w = tid >> 6, lane = tid & 63;
    const int m = lane & 15, q = lane >> 4;
    const int n0 = blockIdx.x * 64 + w * 16;

    const int ut[7] = {4, 22, 10, 16, 12, 14, 13};
    int rows[7];
#pragma unroll
    for (int t = 0; t < 7; ++t) {
        int n = n0 + m;
        rows[t] = (n < N) ? nbr[(size_t)ut[t] * N + n] : -1;
    }
#pragma unroll
    for (int t = 0; t < 7; ++t) {
        const uint16_t* g = (rows[t] >= 0)
            ? y16 + (size_t)rows[t] * 32 + q * 8
            : zrow + q * 8;
        gl_lds16(g, &stage[w][t][0]);
    }
    asm volatile("s_waitcnt vmcnt(0)" ::: "memory");

    f32x4 a[3][2];
#pragma unroll
    for (int g = 0; g < 3; ++g)
#pragma unroll
        for (int ot = 0; ot < 2; ++ot) a[g][ot] = {0.f, 0.f, 0.f, 0.f};

    // edge taps: slot 2e+s2, weight slice t = e*3 + s2*2
#pragma unroll
    for (int e = 0; e < 3; ++e)
#pragma unroll
        for (int s2 = 0; s2 < 2; ++s2) {
            int slot = 2 * e + s2;
            int t = e * 3 + s2 * 2;
            bf16x8 A = *(const bf16x8*)&stage[w][slot][lane * 8];
            const uint16_t* wb = Wf4 + t * 2048 + m * 32 + q * 8;
            bf16x8 B00 = *(const bf16x8*)(wb);
            bf16x8 B10 = *(const bf16x8*)(wb + 1024);
            bf16x8 B01 = *(const bf16x8*)(wb + 512);
            bf16x8 B11 = *(const bf16x8*)(wb + 1536);
            a[e][0] = MFMA_BF16(A, B00, a[e][0]);
            a[e][0] = MFMA_BF16(A, B10, a[e][0]);
            a[e][1] = MFMA_BF16(A, B01, a[e][1]);
            a[e][1] = MFMA_BF16(A, B11, a[e][1]);
        }
    // center tap (slot 6, weight slice kk=1 of each group)
    {
        bf16x8 A6 = *(const bf16x8*)&stage[w][6][lane * 8];
#pragma unroll
        for (int g = 0; g < 3; ++g) {
            const uint16_t* wb = Wf4 + (g * 3 + 1) * 2048 + m * 32 + q * 8;
            bf16x8 B00 = *(const bf16x8*)(wb);
            bf16x8 B10 = *(const bf16x8*)(wb + 1024);
            bf16x8 B01 = *(const bf16x8*)(wb + 512);
            bf16x8 B11 = *(const bf16x8*)(wb + 1536);
            a[g][0] = MFMA_BF16(A6, B00, a[g][0]);
            a[g][0] = MFMA_BF16(A6, B10, a[g][0]);
            a[g][1] = MFMA_BF16(A6, B01, a[g][1]);
            a[g][1] = MFMA_BF16(A6, B11, a[g][1]);
        }
    }

#pragma unroll
    for (int ot = 0; ot < 2; ++ot) {
        int ch = ot * 16 + m;
        float sh[3];
#pragma unroll
        for (int g = 0; g < 3; ++g) {
            const float* p = bnf + (size_t)(4 + g) * 128;
            float scl = p[ch] * rsqrtf(p[96 + ch] + BN_EPS);
            sh[g] = p[32 + ch] - p[64 + ch] * scl;
        }
#pragma unroll
        for (int r = 0; r < 4; ++r) {
            int vox = n0 + q * 4 + r;
            if (vox >= N) continue;
            float g0 = 1.f / (1.f + __expf(-(a[0][ot][r] + sh[0])));
            float g1 = 1.f / (1.f + __expf(-(a[1][ot][r] + sh[1])));
            float g2 = 1.f / (1.f + __expf(-(a[2][ot][r] + sh[2])));
            float o = (g0 + g1 + g2) * bf2f(y16[(size_t)vox * 32 + ch]);
            if (out_f32)
                ((float*)out_)[(size_t)vox * 32 + ch] = o;
            else
                ((uint16_t*)out_)[(size_t)vox * 32 + ch] = f2bf(o);
        }
    }
}

// ---------------------------------------------------------------------------
// Fallback VALU tier (round-4 proven) for tiny ws.
// ---------------------------------------------------------------------------
#define WC_W1   0
#define WC_W12  4608
#define WC_W2   13824
#define WC_W3   18432
#define WC_WR1  27648
#define WC_WR2  30720
#define WC_WR3  33792
#define WC_BNP  36864
#define WC_END  37760

__global__ void canon_weights_fb(WSrcs srcs, float* __restrict__ Wc,
                                 const uint16_t* __restrict__ xprobe)
{
    int f32 = detect_f32_inline(xprobe);
    const int offs[9] = {WC_W1, WC_W12, WC_W2, WC_W3, WC_WR1, WC_WR2,
                         WC_WR3, WC_BNP, WC_END};
    int i = blockIdx.x * 256 + threadIdx.x;
    if (i >= WC_END) return;
    int t = 0;
#pragma unroll
    for (int k = 1; k < 8; ++k) if (i >= offs[k]) t = k;
    Wc[i] = readw(srcs.p[t], i - offs[t], f32);
}

__global__ void canon_x_bf(const void* __restrict__ xsrc,
                           uint16_t* __restrict__ xc, int n)
{
    int f32 = detect_f32_inline((const uint16_t*)xsrc);
    for (int i = blockIdx.x * blockDim.x + threadIdx.x; i < n;
         i += gridDim.x * blockDim.x) {
        float v = f32 ? ((const float*)xsrc)[i]
                      : bf2f(((const uint16_t*)xsrc)[i]);
        xc[i] = f2bf(v);
    }
}

template<int CIN>
__launch_bounds__(256)
__global__ void conv_bn_lrelu_bf(const uint16_t* __restrict__ feat,
                                 const int* __restrict__ nbr,
                                 const float* __restrict__ Wg,
                                 const float* __restrict__ bnp,
                                 const uint16_t* __restrict__ addsrc,
                                 uint16_t* __restrict__ out,
                                 Taps9 taps, int N)
{
    __shared__ float Wl[9 * CIN * 32];
    __shared__ float fs[CIN][128];
    __shared__ int   sidx[128];
    __shared__ float bns[32], bnb[32];

    const int tid = threadIdx.x;
    const int n0  = blockIdx.x * 128;

    for (int i = tid; i < 9 * CIN * 32; i += 256) Wl[i] = Wg[i];
    if (tid < 32) {
        float g = bnp[tid], b = bnp[32 + tid];
        float mu = bnp[64 + tid], va = bnp[96 + tid];
        float s = g * rsqrtf(va + BN_EPS);
        bns[tid] = s; bnb[tid] = b - mu * s;
    }
    float acc[4][4];
#pragma unroll
    for (int v = 0; v < 4; ++v)
#pragma unroll
        for (int j = 0; j < 4; ++j) acc[v][j] = 0.f;

    const int vb = (tid >> 3) << 2, cg = (tid & 7) << 2;
    const int r = tid >> 1, h = tid & 1, j0 = h * (CIN / 2);

#pragma unroll 1
    for (int t = 0; t < 9; ++t) {
        __syncthreads();
        if (tid < 128) {
            int n = n0 + tid;
            sidx[tid] = (n < N) ? nbr[(size_t)taps.t[t] * N + n] : -1;
        }
        __syncthreads();
        int mm = sidx[r];
        if (mm >= 0) {
            const uint16_t* src = feat + (size_t)mm * CIN + j0;
#pragma unroll
            for (int qq = 0; qq < CIN / 2; qq += 8) {
                uint4 u = *reinterpret_cast<const uint4*>(src + qq);
                fs[j0 + qq + 0][r] = bflo(u.x); fs[j0 + qq + 1][r] = bfhi(u.x);
                fs[j0 + qq + 2][r] = bflo(u.y); fs[j0 + qq + 3][r] = bfhi(u.y);
                fs[j0 + qq + 4][r] = bflo(u.z); fs[j0 + qq + 5][r] = bfhi(u.z);
                fs[j0 + qq + 6][r] = bflo(u.w); fs[j0 + qq + 7][r] = bfhi(u.w);
            }
        } else {
#pragma unroll
            for (int qq = 0; qq < CIN / 2; ++qq) fs[j0 + qq][r] = 0.f;
        }
        __syncthreads();
        const float* wk = Wl + t * (CIN * 32) + cg;
#pragma unroll
        for (int ci = 0; ci < CIN; ++ci) {
            float4 f = *reinterpret_cast<const float4*>(&fs[ci][vb]);
            float4 w = *reinterpret_cast<const float4*>(wk + ci * 32);
            acc[0][0] += f.x * w.x; acc[0][1] += f.x * w.y; acc[0][2] += f.x * w.z; acc[0][3] += f.x * w.w;
            acc[1][0] += f.y * w.x; acc[1][1] += f.y * w.y; acc[1][2] += f.y * w.z; acc[1][3] += f.y * w.w;
            acc[2][0] += f.z * w.x; acc[2][1] += f.z * w.y; acc[2][2] += f.z * w.z; acc[2][3] += f.z * w.w;
            acc[3][0] += f.w * w.x; acc[3][1] += f.w * w.y; acc[3][2] += f.w * w.z; acc[3][3] += f.w * w.w;
        }
    }
#pragma unroll
    for (int v = 0; v < 4; ++v) {
        int n = n0 + vb + v;
        if (n >= N) continue;
        ushort4 st;
        uint16_t* ov = (uint16_t*)&st;
#pragma unroll
        for (int j = 0; j < 4; ++j) {
            float x = acc[v][j];
            x = (x >= 0.f) ? x : SLOPE * x;
            float o = x * bns[cg + j] + bnb[cg + j];
            if (addsrc) o += bf2f(addsrc[(size_t)n * 32 + cg + j]);
            ov[j] = f2bf(o);
        }
        *reinterpret_cast<ushort4*>(out + (size_t)n * 32 + cg) = st;
    }
}

__launch_bounds__(256, 4)
__global__ void recon_gate_bf(const uint16_t* __restrict__ y,
                              const int* __restrict__ nbr,
                              const float* __restrict__ Wc,
                              const uint16_t* __restrict__ xprobe,
                              void* __restrict__ out_, int N)
{
    __shared__ float Wl[3 * 32 * 32];
    __shared__ float fs[32][128];
    __shared__ int   sidx[128];
    __shared__ float scl[3][32], shf[3][32];

    const int tid = threadIdx.x;
    const int n0  = blockIdx.x * 128;
    const int out_f32 = detect_f32_inline(xprobe);

    if (tid < 96) {
        int g = tid >> 5, c = tid & 31;
        const float* p = Wc + WC_BNP + (size_t)(4 + g) * 128;
        float ga = p[c], be = p[32 + c], mu = p[64 + c], va = p[96 + c];
        float s = ga * rsqrtf(va + BN_EPS);
        scl[g][c] = s; shf[g][c] = be - mu * s;
    }
    const int vb = (tid >> 3) << 2, cg = (tid & 7) << 2;
    const int r = tid >> 1, h = tid & 1, j0 = h * 16;

    float gsum[4][4];
#pragma unroll
    for (int v = 0; v < 4; ++v)
#pragma unroll
        for (int j = 0; j < 4; ++j) gsum[v][j] = 0.f;

    const int taps[3][3] = {{4, 13, 22}, {10, 13, 16}, {12, 13, 14}};

#pragma unroll 1
    for (int g = 0; g < 3; ++g) {
        __syncthreads();
        {
            const float* src = Wc + WC_WR1 + g * 3072;
            for (int i = tid; i < 3072; i += 256)
                Wl[i] = src[i] * scl[g][i & 31];
        }
        float acc[4][4];
#pragma unroll
        for (int v = 0; v < 4; ++v)
#pragma unroll
            for (int j = 0; j < 4; ++j) acc[v][j] = 0.f;

#pragma unroll 1
        for (int k = 0; k < 3; ++k) {
            __syncthreads();
            if (tid < 128) {
                int n = n0 + tid;
                sidx[tid] = (n < N) ? nbr[(size_t)taps[g][k] * N + n] : -1;
            }
            __syncthreads();
            int mm = sidx[r];
            if (mm >= 0) {
                const uint16_t* src = y + (size_t)mm * 32 + j0;
#pragma unroll
                for (int qq = 0; qq < 16; qq += 8) {
                    uint4 u = *reinterpret_cast<const uint4*>(src + qq);
                    fs[j0 + qq + 0][r] = bflo(u.x); fs[j0 + qq + 1][r] = bfhi(u.x);
                    fs[j0 + qq + 2][r] = bflo(u.y); fs[j0 + qq + 3][r] = bfhi(u.y);
                    fs[j0 + qq + 4][r] = bflo(u.z); fs[j0 + qq + 5][r] = bfhi(u.z);
                    fs[j0 + qq + 6][r] = bflo(u.w); fs[j0 + qq + 7][r] = bfhi(u.w);
                }
            } else {
#pragma unroll
                for (int qq = 0; qq < 16; ++qq) fs[j0 + qq][r] = 0.f;
            }
            __syncthreads();
            const float* wk = Wl + k * (32 * 32) + cg;
#pragma unroll
            for (int ci = 0; ci < 32; ++ci) {
                float4 f = *reinterpret_cast<const float4*>(&fs[ci][vb]);
                float4 w = *reinterpret_cast<const float4*>(wk + ci * 32);
                acc[0][0] += f.x * w.x; acc[0][1] += f.x * w.y; acc[0][2] += f.x * w.z; acc[0][3] += f.x * w.w;
                acc[1][0] += f.y * w.x; acc[1][1] += f.y * w.y; acc[1][2] += f.y * w.z; acc[1][3] += f.y * w.w;
                acc[2][0] += f.z * w.x; acc[2][1] += f.z * w.y; acc[2][2] += f.z * w.z; acc[2][3] += f.z * w.w;
                acc[3][0] += f.w * w.x; acc[3][1] += f.w * w.y; acc[3][2] += f.w * w.z; acc[3][3] += f.w * w.w;
            }
        }
#pragma unroll
        for (int v = 0; v < 4; ++v)
#pragma unroll
            for (int j = 0; j < 4; ++j) {
                float x = acc[v][j] + shf[g][cg + j];
                gsum[v][j] += 1.f / (1.f + __expf(-x));
            }
    }
#pragma unroll
    for (int v = 0; v < 4; ++v) {
        int n = n0 + vb + v;
        if (n >= N) continue;
#pragma unroll
        for (int j = 0; j < 4; ++j) {
            float yv = bf2f(y[(size_t)n * 32 + cg + j]);
            float o = gsum[v][j] * yv;
            if (out_f32) ((float*)out_)[(size_t)n * 32 + cg + j] = o;
            else ((uint16_t*)out_)[(size_t)n * 32 + cg + j] = f2bf(o);
        }
    }
}

// ---------------------------------------------------------------------------
extern "C" void kernel_launch(void* const* d_in, const int* in_sizes, int n_in,
                              void* d_out, int out_size, void* d_ws, size_t ws_size,
                              hipStream_t stream)
{
    (void)n_in; (void)out_size;
    const void* x   = d_in[0];
    const int*  nbr = (const int*)d_in[1];
    const int N = in_sizes[0] / 16;
    const uint16_t* xprobe = (const uint16_t*)x;

    dim3 block(256);
    const int gx2 = (N + 63) / 64;
    Taps9 p133 = {{9, 10, 11, 12, 13, 14, 15, 16, 17}};
    Taps9 p313 = {{3, 4, 5, 12, 13, 14, 21, 22, 23}};
    WSrcs ws8 = {{ d_in[2], d_in[3], d_in[4], d_in[5],
                   d_in[6], d_in[7], d_in[8], d_in[9] }};

    // ws layout (MFMA tier): bnf+zrow [0,4096) | Wf [4096, 188416) | xi|A1|A2|B1
    float*    bnf = (float*)d_ws;
    const uint16_t* zrow = (const uint16_t*)((char*)d_ws + ZROW_OFF);
    uint16_t* Wf  = (uint16_t*)((char*)d_ws + 4096);
    const size_t base2 = 4096u + (size_t)WF_END * 2;   // 188416
    uint16_t* xi  = (uint16_t*)((char*)d_ws + base2);  // [N][32] interleaved
    uint16_t* A1  = xi + (size_t)N * 32;               // [N][32] bf16-hi
    uint16_t* A2  = A1 + (size_t)N * 32;
    uint16_t* B1  = A2 + (size_t)N * 32;
    const size_t need = base2 + 4u * (size_t)N * 64;

    if (ws_size >= need) {
        prep_all<<<(WF_END + BN_CNT + 64 + 255) / 256, block, 0, stream>>>(xprobe, ws8, Wf, bnf);
        canon_x3<<<1024, block, 0, stream>>>(x, (uint32_t*)xi, N * 16);
        ConvJob c1  = {xi, Wf + 0 * WFS, bnf + 0 * 128, nullptr, A1, p133};
        ConvJob c2  = {xi, Wf + 2 * WFS, bnf + 2 * 128, nullptr, A2, p313};
        ConvJob c12 = {A1, Wf + 1 * WFS, bnf + 1 * 128, nullptr, B1, p313};
        ConvJob c3  = {A2, Wf + 3 * WFS, bnf + 3 * 128, B1,      A1, p133};
        conv_mfma6<<<dim3(gx2, 2), block, 0, stream>>>(c1, c2, nbr, zrow, N);   // s1, r1
        conv_mfma6<<<dim3(gx2, 1), block, 0, stream>>>(c12, c12, nbr, zrow, N); // s
        conv_mfma6<<<dim3(gx2, 1), block, 0, stream>>>(c3, c3, nbr, zrow, N);   // y = r+s
        recon_mfma6<<<gx2, block, 0, stream>>>(A1, xprobe, nbr, Wf + 4 * WFS, bnf, zrow, d_out, N);
    } else {
        // VALU fallback (all-bf16)
        float*    Wc = (float*)d_ws;
        uint16_t* xc = (uint16_t*)((char*)d_ws + (size_t)WC_END * 4 + 256);
        uint16_t* A  = (uint16_t*)d_out;
        uint16_t* B  = xc + (size_t)N * 16;
        const float* bn0 = Wc + WC_BNP + 0 * 128;
        const float* bn1 = Wc + WC_BNP + 1 * 128;
        const float* bn2 = Wc + WC_BNP + 2 * 128;
        const float* bn3 = Wc + WC_BNP + 3 * 128;
        const int gx = (N + 127) / 128;
        canon_weights_fb<<<(WC_END + 255) / 256, block, 0, stream>>>(ws8, Wc, xprobe);
        canon_x_bf<<<1024, block, 0, stream>>>(x, xc, N * 16);
        conv_bn_lrelu_bf<16><<<gx, block, 0, stream>>>(xc, nbr, Wc + WC_W1,  bn0, nullptr, A, p133, N);
        conv_bn_lrelu_bf<32><<<gx, block, 0, stream>>>(A,  nbr, Wc + WC_W12, bn1, nullptr, B, p313, N);
        conv_bn_lrelu_bf<16><<<gx, block, 0, stream>>>(xc, nbr, Wc + WC_W2,  bn2, nullptr, A, p313, N);
        conv_bn_lrelu_bf<32><<<gx, block, 0, stream>>>(A,  nbr, Wc + WC_W3,  bn3, B,       B, p133, N);
        recon_gate_bf<<<gx, block, 0, stream>>>(B, nbr, Wc, xprobe, d_out, N);
    }
}